// Round 4
// baseline (164.019 us; speedup 1.0000x reference)
//
#include <hip/hip_runtime.h>

#define SEQ_L 512
#define DIM 256

typedef float f4 __attribute__((ext_vector_type(4)));

// ---------------------------------------------------------------------------
// Kernel A: out_row = l2norm(X_row @ W + b) for q/k/v, selected by blockIdx.y.
// 8 rows/block, 256 threads (thread t owns output column t). x broadcast from
// LDS as f4 (ds_read_b128) -> 4x fewer DS ops than scalar broadcast.
// ---------------------------------------------------------------------------
__global__ __launch_bounds__(256) void proj_norm3_kernel(
    const float* __restrict__ Xq, const float* __restrict__ Wq,
    const float* __restrict__ bq, float* __restrict__ oq,
    const float* __restrict__ Xk, const float* __restrict__ Wk,
    const float* __restrict__ bk, float* __restrict__ ok,
    const float* __restrict__ Xv, const float* __restrict__ Wv,
    const float* __restrict__ bv, float* __restrict__ ov)
{
    const float* X; const float* W; const float* bias; float* out;
    if (blockIdx.y == 0)      { X = Xq; W = Wq; bias = bq; out = oq; }
    else if (blockIdx.y == 1) { X = Xk; W = Wk; bias = bk; out = ok; }
    else                      { X = Xv; W = Wv; bias = bv; out = ov; }

    const int ROWS = 8;
    __shared__ __align__(16) float xs[ROWS][DIM];
    __shared__ float red[ROWS][4];

    const int t  = threadIdx.x;
    const int r0 = blockIdx.x * ROWS;

    #pragma unroll
    for (int r = 0; r < ROWS; ++r)
        xs[r][t] = X[(size_t)(r0 + r) * DIM + t];
    __syncthreads();

    const float b = bias[t];
    float acc[ROWS];
    #pragma unroll
    for (int r = 0; r < ROWS; ++r) acc[r] = b;

    for (int d4 = 0; d4 < DIM / 4; ++d4) {
        const float w0 = W[(size_t)(d4 * 4 + 0) * DIM + t];
        const float w1 = W[(size_t)(d4 * 4 + 1) * DIM + t];
        const float w2 = W[(size_t)(d4 * 4 + 2) * DIM + t];
        const float w3 = W[(size_t)(d4 * 4 + 3) * DIM + t];
        #pragma unroll
        for (int r = 0; r < ROWS; ++r) {
            const f4 xv = ((const f4*)xs[r])[d4];   // LDS broadcast, b128
            acc[r] += xv.x * w0 + xv.y * w1 + xv.z * w2 + xv.w * w3;
        }
    }

    const int lane = t & 63;
    const int wid  = t >> 6;

    #pragma unroll
    for (int r = 0; r < ROWS; ++r) {
        float ss = acc[r] * acc[r];
        #pragma unroll
        for (int off = 32; off >= 1; off >>= 1)
            ss += __shfl_down(ss, off, 64);
        if (lane == 0) red[r][wid] = ss;
    }
    __syncthreads();

    #pragma unroll
    for (int r = 0; r < ROWS; ++r) {
        const float s = red[r][0] + red[r][1] + red[r][2] + red[r][3];
        const float scale = rsqrtf(fmaxf(s, 1e-12f));
        out[(size_t)(r0 + r) * DIM + t] = acc[r] * scale;
    }
}

// ---------------------------------------------------------------------------
// Kernel B: out[b,l,m] = 0.025 * dot(q[b,l], k[b,m])   (qk term, L2-resident k)
// ---------------------------------------------------------------------------
__global__ __launch_bounds__(256) void qk4_kernel(
    const float* __restrict__ q, const float* __restrict__ k,
    float* __restrict__ out)
{
    const int l0    = blockIdx.x * 4;
    const int b     = l0 >> 9;
    const int lane  = threadIdx.x & 63;
    const int wave  = threadIdx.x >> 6;
    const int m_sub = lane & 7;
    const int d_sub = lane >> 3;

    f4 qf[4][8];
    #pragma unroll
    for (int r = 0; r < 4; ++r) {
        const f4* q4 = (const f4*)(q + (size_t)(l0 + r) * DIM);
        #pragma unroll
        for (int c = 0; c < 8; ++c) qf[r][c] = q4[c * 8 + d_sub];
    }

    const f4* k4 = (const f4*)(k + (size_t)b * SEQ_L * DIM);

    for (int m0 = wave * 8; m0 < SEQ_L; m0 += 32) {
        const size_t base = (size_t)(m0 + m_sub) * (DIM / 4) + d_sub;
        f4 kf[8];
        #pragma unroll
        for (int c = 0; c < 8; ++c) kf[c] = k4[base + c * 8];

        #pragma unroll
        for (int r = 0; r < 4; ++r) {
            float sa = 0.f, sb = 0.f;
            #pragma unroll
            for (int c = 0; c < 8; ++c) {
                sa += qf[r][c].x * kf[c].x + qf[r][c].y * kf[c].y;
                sb += qf[r][c].z * kf[c].z + qf[r][c].w * kf[c].w;
            }
            float s = sa + sb;
            s += __shfl_xor(s, 8, 64);
            s += __shfl_xor(s, 16, 64);
            s += __shfl_xor(s, 32, 64);
            if (lane < 8)
                out[(size_t)(l0 + r) * SEQ_L + m0 + lane] = s * 0.025f;
        }
    }
}

// ---------------------------------------------------------------------------
// Kernel C: out[b,l,m] += 0.0375 * dot(q[b,l], edge[b,l,m])   (HBM stream)
// Depth-2 ping-pong pipeline: issue group g+1's loads (incl. RMW base)
// BEFORE reducing group g -> every wave keeps >=9 loads in flight through
// the compute/shuffle/store phase. One block per (b,l) row; each of 4 waves
// runs 16 groups of 8 m's (m = wave*8 + i*32).
// ---------------------------------------------------------------------------
__global__ __launch_bounds__(256) void edge_kernel(
    const float* __restrict__ q, const float* __restrict__ edge,
    float* __restrict__ out)
{
    const int bl    = blockIdx.x;
    const int lane  = threadIdx.x & 63;
    const int wave  = threadIdx.x >> 6;
    const int m_sub = lane & 7;
    const int d_sub = lane >> 3;

    const f4* q4 = (const f4*)(q + (size_t)bl * DIM);
    f4 qf[8];
    #pragma unroll
    for (int c = 0; c < 8; ++c) qf[c] = q4[c * 8 + d_sub];

    const f4* e4 = (const f4*)(edge + (size_t)bl * SEQ_L * DIM);
    float* orow = out + (size_t)bl * SEQ_L;

    f4 eA[8], eB[8];
    float baseA, baseB;
    const int mw = wave * 8;   // group i -> m = mw + i*32, i in [0,16)

#define LOADG(BUF, BASEV, MI) do {                                          \
        const size_t ba_ = (size_t)((MI) + m_sub) * (DIM / 4) + d_sub;      \
        _Pragma("unroll")                                                   \
        for (int c_ = 0; c_ < 8; ++c_) BUF[c_] = e4[ba_ + c_ * 8];          \
        BASEV = (lane < 8) ? orow[(MI) + lane] : 0.f;                       \
    } while (0)

#define COMPG(BUF, BASEV, MI) do {                                          \
        float sa_ = 0.f, sb_ = 0.f;                                         \
        _Pragma("unroll")                                                   \
        for (int c_ = 0; c_ < 8; ++c_) {                                    \
            sa_ += qf[c_].x * BUF[c_].x + qf[c_].y * BUF[c_].y;             \
            sb_ += qf[c_].z * BUF[c_].z + qf[c_].w * BUF[c_].w;             \
        }                                                                   \
        float s_ = sa_ + sb_;                                               \
        s_ += __shfl_xor(s_, 8, 64);                                        \
        s_ += __shfl_xor(s_, 16, 64);                                       \
        s_ += __shfl_xor(s_, 32, 64);                                       \
        if (lane < 8) orow[(MI) + lane] = fmaf(s_, 0.0375f, BASEV);         \
    } while (0)

    LOADG(eA, baseA, mw + 0 * 32);
    #pragma unroll
    for (int i = 0; i < 8; ++i) {
        LOADG(eB, baseB, mw + (2 * i + 1) * 32);
        COMPG(eA, baseA, mw + (2 * i) * 32);
        if (i < 7) LOADG(eA, baseA, mw + (2 * i + 2) * 32);
        COMPG(eB, baseB, mw + (2 * i + 1) * 32);
    }

#undef LOADG
#undef COMPG
}

// ---------------------------------------------------------------------------
// Host launcher
// ---------------------------------------------------------------------------
extern "C" void kernel_launch(void* const* d_in, const int* in_sizes, int n_in,
                              void* d_out, int out_size, void* d_ws, size_t ws_size,
                              hipStream_t stream) {
    const float* queries = (const float*)d_in[0];
    const float* keys    = (const float*)d_in[1];
    const float* values  = (const float*)d_in[2];
    // d_in[3] = relative_encoding_lookup: DEAD CODE (overwritten in reference).
    const float* edge    = (const float*)d_in[4];
    const float* Wq = (const float*)d_in[5];
    const float* bq = (const float*)d_in[6];
    const float* Wk = (const float*)d_in[7];
    const float* bk = (const float*)d_in[8];
    const float* Wv = (const float*)d_in[9];
    const float* bv = (const float*)d_in[10];

    float* out = (float*)d_out;

    const int B = in_sizes[0] / (SEQ_L * DIM);           // 2
    const size_t scores_sz = (size_t)B * SEQ_L * SEQ_L;
    const size_t qkv_sz    = (size_t)B * SEQ_L * DIM;

    float* v_out = out + scores_sz;           // output slot 1: v
    float* q_out = out + scores_sz + qkv_sz;  // output slot 2: q
    float* k_ws  = (float*)d_ws;              // k -> scratch

    const int rows = B * SEQ_L;               // 1024

    dim3 pgrid(rows / 8, 3);
    proj_norm3_kernel<<<pgrid, 256, 0, stream>>>(
        queries, Wq, bq, q_out,
        keys,    Wk, bk, k_ws,
        values,  Wv, bv, v_out);

    qk4_kernel<<<rows / 4, 256, 0, stream>>>(q_out, k_ws, out);

    edge_kernel<<<rows, 256, 0, stream>>>(q_out, edge, out);
}

// Round 5
// 148.454 us; speedup vs baseline: 1.1049x; 1.1049x over previous
//
#include <hip/hip_runtime.h>

#define SEQ_L 512
#define DIM 256

typedef float f4 __attribute__((ext_vector_type(4)));

// ---------------------------------------------------------------------------
// Kernel A: out_row = l2norm(X_row @ W + b) for q/k/v, selected by blockIdx.y.
// 8 rows/block, 256 threads (thread t owns output column t).
// ---------------------------------------------------------------------------
__global__ __launch_bounds__(256) void proj_norm3_kernel(
    const float* __restrict__ Xq, const float* __restrict__ Wq,
    const float* __restrict__ bq, float* __restrict__ oq,
    const float* __restrict__ Xk, const float* __restrict__ Wk,
    const float* __restrict__ bk, float* __restrict__ ok,
    const float* __restrict__ Xv, const float* __restrict__ Wv,
    const float* __restrict__ bv, float* __restrict__ ov)
{
    const float* X; const float* W; const float* bias; float* out;
    if (blockIdx.y == 0)      { X = Xq; W = Wq; bias = bq; out = oq; }
    else if (blockIdx.y == 1) { X = Xk; W = Wk; bias = bk; out = ok; }
    else                      { X = Xv; W = Wv; bias = bv; out = ov; }

    const int ROWS = 8;
    __shared__ __align__(16) float xs[ROWS][DIM];
    __shared__ float red[ROWS][4];

    const int t  = threadIdx.x;
    const int r0 = blockIdx.x * ROWS;

    #pragma unroll
    for (int r = 0; r < ROWS; ++r)
        xs[r][t] = X[(size_t)(r0 + r) * DIM + t];
    __syncthreads();

    const float b = bias[t];
    float acc[ROWS];
    #pragma unroll
    for (int r = 0; r < ROWS; ++r) acc[r] = b;

    #pragma unroll 2
    for (int d4 = 0; d4 < DIM / 4; ++d4) {
        const float w0 = W[(size_t)(d4 * 4 + 0) * DIM + t];
        const float w1 = W[(size_t)(d4 * 4 + 1) * DIM + t];
        const float w2 = W[(size_t)(d4 * 4 + 2) * DIM + t];
        const float w3 = W[(size_t)(d4 * 4 + 3) * DIM + t];
        #pragma unroll
        for (int r = 0; r < ROWS; ++r) {
            const f4 xv = ((const f4*)xs[r])[d4];   // LDS broadcast, b128
            acc[r] += xv.x * w0 + xv.y * w1 + xv.z * w2 + xv.w * w3;
        }
    }

    const int lane = t & 63;
    const int wid  = t >> 6;

    #pragma unroll
    for (int r = 0; r < ROWS; ++r) {
        float ss = acc[r] * acc[r];
        #pragma unroll
        for (int off = 32; off >= 1; off >>= 1)
            ss += __shfl_down(ss, off, 64);
        if (lane == 0) red[r][wid] = ss;
    }
    __syncthreads();

    #pragma unroll
    for (int r = 0; r < ROWS; ++r) {
        const float s = red[r][0] + red[r][1] + red[r][2] + red[r][3];
        const float scale = rsqrtf(fmaxf(s, 1e-12f));
        out[(size_t)(r0 + r) * DIM + t] = acc[r] * scale;
    }
}

// ---------------------------------------------------------------------------
// Kernel B: fused qk + edge.
//   out[b,l,m] = 0.025*dot(q[b,l],k[b,m]) + 0.0375*dot(q[b,l],edge[b,l,m])
//
// Grid (1024 rows, 4). Block (bl, y) covers m in [y*128, y*128+128).
// Each wave owns 4 groups of 8 m's: m = mbase + wave*8 + g*32.
//
// Phase 1: qk term from L2-resident k -> 4 register scalars (qkr[g]),
//          3-step __shfl_xor butterfly per group.
// Phase 2: edge HBM stream, R3's compiler-scheduled double-group loop
//          (NT loads, 16 KB per iteration), single write of out (no RMW).
// ---------------------------------------------------------------------------
__global__ __launch_bounds__(256) void qk_edge_kernel(
    const float* __restrict__ q, const float* __restrict__ k,
    const float* __restrict__ edge, float* __restrict__ out)
{
    const int bl    = blockIdx.x;        // b*SEQ_L + l
    const int b     = bl >> 9;
    const int lane  = threadIdx.x & 63;
    const int wave  = threadIdx.x >> 6;
    const int m_sub = lane & 7;
    const int d_sub = lane >> 3;
    const int mw    = blockIdx.y * 128 + wave * 8;   // first group's m0

    // Preload q slices: qf[c] = q[bl][c*32 + d_sub*4 .. +3]
    const f4* q4 = (const f4*)(q + (size_t)bl * DIM);
    f4 qf[8];
    #pragma unroll
    for (int c = 0; c < 8; ++c) qf[c] = q4[c * 8 + d_sub];

    const f4* k4 = (const f4*)(k + (size_t)b * SEQ_L * DIM);
    const f4* e4 = (const f4*)(edge + (size_t)bl * SEQ_L * DIM);
    float* orow = out + (size_t)bl * SEQ_L;

    // ---- phase 1: qk from L2 ----
    float qkr[4];
    #pragma unroll
    for (int g = 0; g < 4; ++g) {
        const size_t ba = (size_t)(mw + g * 32 + m_sub) * (DIM / 4) + d_sub;
        f4 kf[8];
        #pragma unroll
        for (int c = 0; c < 8; ++c) kf[c] = k4[ba + c * 8];
        float sa = 0.f, sb = 0.f;
        #pragma unroll
        for (int c = 0; c < 8; ++c) {
            sa += qf[c].x * kf[c].x + qf[c].y * kf[c].y;
            sb += qf[c].z * kf[c].z + qf[c].w * kf[c].w;
        }
        float s = sa + sb;
        s += __shfl_xor(s, 8, 64);
        s += __shfl_xor(s, 16, 64);
        s += __shfl_xor(s, 32, 64);
        qkr[g] = s * 0.025f;             // valid on every lane (m = m0 + (lane&7))
    }

    // ---- phase 2: edge stream, 2 groups per iteration ----
    #pragma unroll
    for (int i = 0; i < 2; ++i) {
        const int m0 = mw + i * 64;      // group 2i
        const int m1 = m0 + 32;          // group 2i+1
        const size_t ba0 = (size_t)(m0 + m_sub) * (DIM / 4) + d_sub;
        const size_t ba1 = (size_t)(m1 + m_sub) * (DIM / 4) + d_sub;

        f4 e0[8], e1[8];
        #pragma unroll
        for (int c = 0; c < 8; ++c) {
            e0[c] = __builtin_nontemporal_load(&e4[ba0 + c * 8]);
            e1[c] = __builtin_nontemporal_load(&e4[ba1 + c * 8]);
        }

        float sa0 = 0.f, sb0 = 0.f, sa1 = 0.f, sb1 = 0.f;
        #pragma unroll
        for (int c = 0; c < 8; ++c) {
            sa0 += qf[c].x * e0[c].x + qf[c].y * e0[c].y;
            sb0 += qf[c].z * e0[c].z + qf[c].w * e0[c].w;
            sa1 += qf[c].x * e1[c].x + qf[c].y * e1[c].y;
            sb1 += qf[c].z * e1[c].z + qf[c].w * e1[c].w;
        }
        float s0 = sa0 + sb0, s1 = sa1 + sb1;
        s0 += __shfl_xor(s0, 8, 64);  s1 += __shfl_xor(s1, 8, 64);
        s0 += __shfl_xor(s0, 16, 64); s1 += __shfl_xor(s1, 16, 64);
        s0 += __shfl_xor(s0, 32, 64); s1 += __shfl_xor(s1, 32, 64);

        if (lane < 8) {
            orow[m0 + lane] = fmaf(s0, 0.0375f, qkr[2 * i]);
            orow[m1 + lane] = fmaf(s1, 0.0375f, qkr[2 * i + 1]);
        }
    }
}

// ---------------------------------------------------------------------------
// Host launcher
// ---------------------------------------------------------------------------
extern "C" void kernel_launch(void* const* d_in, const int* in_sizes, int n_in,
                              void* d_out, int out_size, void* d_ws, size_t ws_size,
                              hipStream_t stream) {
    const float* queries = (const float*)d_in[0];
    const float* keys    = (const float*)d_in[1];
    const float* values  = (const float*)d_in[2];
    // d_in[3] = relative_encoding_lookup: DEAD CODE (overwritten in reference).
    const float* edge    = (const float*)d_in[4];
    const float* Wq = (const float*)d_in[5];
    const float* bq = (const float*)d_in[6];
    const float* Wk = (const float*)d_in[7];
    const float* bk = (const float*)d_in[8];
    const float* Wv = (const float*)d_in[9];
    const float* bv = (const float*)d_in[10];

    float* out = (float*)d_out;

    const int B = in_sizes[0] / (SEQ_L * DIM);           // 2
    const size_t scores_sz = (size_t)B * SEQ_L * SEQ_L;
    const size_t qkv_sz    = (size_t)B * SEQ_L * DIM;

    float* v_out = out + scores_sz;           // output slot 1: v
    float* q_out = out + scores_sz + qkv_sz;  // output slot 2: q
    float* k_ws  = (float*)d_ws;              // k -> scratch

    const int rows = B * SEQ_L;               // 1024

    dim3 pgrid(rows / 8, 3);
    proj_norm3_kernel<<<pgrid, 256, 0, stream>>>(
        queries, Wq, bq, q_out,
        keys,    Wk, bk, k_ws,
        values,  Wv, bv, v_out);

    dim3 egrid(rows, 4);
    qk_edge_kernel<<<egrid, 256, 0, stream>>>(q_out, k_ws, edge, out);
}